// Round 2
// baseline (638.760 us; speedup 1.0000x reference)
//
#include <hip/hip_runtime.h>
#include <stdint.h>
#include <stddef.h>

// Problem constants (fixed by setup_inputs)
#define N_ROWS 500000
#define DDIM   128
#define K2     256      // 2*D
#define KBOND  32
#define TILE_ROWS 64
#define NT ((N_ROWS + TILE_ROWS - 1) / TILE_ROWS)   // 7813
#define NB1 2048        // pass1 grid (grid-stride over tiles)
#define P2_BLOCKS 2048

typedef float  f32x4  __attribute__((ext_vector_type(4)));
typedef __bf16 bf16x8 __attribute__((ext_vector_type(8)));
typedef __bf16 bf16x4 __attribute__((ext_vector_type(4)));

// ---- module-scope device scratch: no dependence on d_ws/ws_size ----
__device__ __bf16 g_wbf[DDIM * K2];                    // 64 KiB  (W_i_w bf16, [d][k])
__device__ float  g_partials[NB1 * DDIM];              // 1 MiB
__device__ float  g_m[DDIM];
__device__ float  g_msg[DDIM];
__device__ __bf16 g_hn[(size_t)N_ROWS * DDIM];         // 128 MiB (h_n bf16)

// ---- kernel 1: W_i_w f32 -> bf16 (natural [d][k] layout) ----
__global__ void k_prep(const float* __restrict__ w) {
  int t = blockIdx.x * blockDim.x + threadIdx.x;
  if (t < DDIM * K2) g_wbf[t] = (__bf16)w[t];          // RNE convert
}

// ---- kernel 2: fused h_n GEMM + m partial accumulation ----
// block = 256 threads = 4 waves; block tile = 64 rows x 128 cols; wave = 16 rows x 128 cols
// MFMA 16x16x32 bf16 via builtin (compiler handles all MFMA hazards).
// Layout (verified m89): D: lane l, reg r -> row=(l>>4)*4+r, col=l&15.
// A/B k-map: we load A and B with the IDENTICAL (group,elem)->k map, so any
// hardware k-permutation cancels in the dot product.
__global__ __launch_bounds__(256)
void k_pass1(const float* __restrict__ x, const float* __restrict__ he,
             const float* __restrict__ bond, const float* __restrict__ bias)
{
  __shared__ float s_lds[TILE_ROWS];
  __shared__ float mred[4][DDIM];

  const int wave = threadIdx.x >> 6;
  const int lane = threadIdx.x & 63;
  const int l15  = lane & 15;
  const int g    = lane >> 4;        // 0..3

  float macc[8];
  #pragma unroll
  for (int i = 0; i < 8; ++i) macc[i] = 0.f;

  // bias for this lane's 8 column-fragments (tile-invariant)
  float bv[8];
  #pragma unroll
  for (int cf = 0; cf < 8; ++cf) bv[cf] = bias[cf * 16 + l15];

  for (int tile = blockIdx.x; tile < NT; tile += gridDim.x) {
    const int rb_blk = tile * TILE_ROWS;

    // s[n] = sum_k bond[k][n] for the block's 64 rows (threads 0..63, coalesced per k)
    if (threadIdx.x < TILE_ROWS) {
      int n = rb_blk + threadIdx.x;
      float s = 0.f;
      if (n < N_ROWS) {
        #pragma unroll
        for (int k = 0; k < KBOND; ++k) s += bond[(size_t)k * N_ROWS + n];
      }
      s_lds[threadIdx.x] = s;
    }
    __syncthreads();

    const int rb     = rb_blk + wave * 16;
    int arow         = rb + l15;
    int arow_c       = arow < N_ROWS ? arow : (N_ROWS - 1);
    const float* xrow  = x  + (size_t)arow_c * DDIM;
    const float* herow = he + (size_t)arow_c * DDIM;

    f32x4 acc[8];
    #pragma unroll
    for (int i = 0; i < 8; ++i) acc[i] = (f32x4)(0.f);

    #pragma unroll 1
    for (int ks = 0; ks < 8; ++ks) {
      const int kb = ks * 32;
      const int k0 = kb + 4 * g;
      const float* src = (kb < DDIM) ? xrow : (herow - DDIM);
      f32x4 a0 = *(const f32x4*)(src + k0);
      f32x4 a1 = *(const f32x4*)(src + k0 + 16);
      bf16x8 af;
      #pragma unroll
      for (int i = 0; i < 4; ++i) {
        af[i]     = (__bf16)a0[i];
        af[4 + i] = (__bf16)a1[i];
      }
      const __bf16* wp = g_wbf + (size_t)l15 * K2 + k0;
      #pragma unroll
      for (int cf = 0; cf < 8; ++cf) {
        const __bf16* wc = wp + (size_t)cf * 16 * K2;
        bf16x4 b0 = *(const bf16x4*)(wc);
        bf16x4 b1 = *(const bf16x4*)(wc + 16);
        bf16x8 bf;
        #pragma unroll
        for (int i = 0; i < 4; ++i) {
          bf[i]     = b0[i];
          bf[4 + i] = b1[i];
        }
        acc[cf] = __builtin_amdgcn_mfma_f32_16x16x32_bf16(af, bf, acc[cf], 0, 0, 0);
      }
    }

    // epilogue: bias + relu, store h_n (bf16), accumulate m partial
    #pragma unroll
    for (int cf = 0; cf < 8; ++cf) {
      const int col = cf * 16 + l15;
      #pragma unroll
      for (int i = 0; i < 4; ++i) {
        const int lr = wave * 16 + g * 4 + i;   // row within block tile
        const int r  = rb_blk + lr;
        float h = acc[cf][i] + bv[cf];
        h = h > 0.f ? h : 0.f;
        macc[cf] += s_lds[lr] * h;              // s_lds==0 for OOB rows
        if (r < N_ROWS) g_hn[(size_t)r * DDIM + col] = (__bf16)h;
      }
    }
    __syncthreads();   // protect s_lds for next tile
  }

  // m partial: reduce across the 4 lane-groups, then across waves, write block partial
  #pragma unroll
  for (int cf = 0; cf < 8; ++cf) {
    macc[cf] += __shfl_xor(macc[cf], 16, 64);
    macc[cf] += __shfl_xor(macc[cf], 32, 64);
  }
  if (lane < 16) {
    #pragma unroll
    for (int cf = 0; cf < 8; ++cf) mred[wave][cf * 16 + lane] = macc[cf];
  }
  __syncthreads();
  if (threadIdx.x < DDIM) {
    float v = mred[0][threadIdx.x] + mred[1][threadIdx.x] +
              mred[2][threadIdx.x] + mred[3][threadIdx.x];
    g_partials[(size_t)blockIdx.x * DDIM + threadIdx.x] = v;
  }
}

// ---- kernel 3: reduce partials -> m[128] (one block per d) ----
__global__ void k_mreduce() {
  const int d = blockIdx.x;
  float s = 0.f;
  for (int i = threadIdx.x; i < NB1; i += 256) s += g_partials[(size_t)i * DDIM + d];
  #pragma unroll
  for (int off = 32; off >= 1; off >>= 1) s += __shfl_down(s, off, 64);
  __shared__ float red[4];
  if ((threadIdx.x & 63) == 0) red[threadIdx.x >> 6] = s;
  __syncthreads();
  if (threadIdx.x == 0) g_m[d] = red[0] + red[1] + red[2] + red[3];
}

// ---- kernel 4: msg[d] = b_m[d] + sum_j m[j] * W_m_w[d][j] ----
__global__ void k_msg(const float* __restrict__ wm, const float* __restrict__ bm) {
  __shared__ float ms[DDIM];
  if (threadIdx.x < DDIM) ms[threadIdx.x] = g_m[threadIdx.x];
  __syncthreads();
  const int d = threadIdx.x;
  if (d < DDIM) {
    float acc = bm[d];
    #pragma unroll 8
    for (int j = 0; j < DDIM; ++j) acc += ms[j] * wm[(size_t)d * DDIM + j];
    g_msg[d] = acc;
  }
}

// ---- kernel 5: out = relu(h_n + msg) ----
__global__ __launch_bounds__(256)
void k_pass2(float* __restrict__ out)
{
  __shared__ float ms[DDIM];
  if (threadIdx.x < DDIM) ms[threadIdx.x] = g_msg[threadIdx.x];
  __syncthreads();
  const size_t total = (size_t)N_ROWS * DDIM / 8;   // 8 elems per chunk
  for (size_t c = (size_t)blockIdx.x * blockDim.x + threadIdx.x; c < total;
       c += (size_t)gridDim.x * blockDim.x) {
    const size_t base = c * 8;
    const int col0 = (int)(base & (DDIM - 1));
    bf16x8 hv = *(const bf16x8*)(g_hn + base);
    f32x4 o0, o1;
    #pragma unroll
    for (int i = 0; i < 4; ++i) {
      float a = (float)hv[i]     + ms[col0 + i];
      float b = (float)hv[4 + i] + ms[col0 + 4 + i];
      o0[i] = a > 0.f ? a : 0.f;
      o1[i] = b > 0.f ? b : 0.f;
    }
    *(f32x4*)(out + base)     = o0;
    *(f32x4*)(out + base + 4) = o1;
  }
}

extern "C" void kernel_launch(void* const* d_in, const int* in_sizes, int n_in,
                              void* d_out, int out_size, void* d_ws, size_t ws_size,
                              hipStream_t stream) {
  const float* x    = (const float*)d_in[0];
  const float* he   = (const float*)d_in[1];
  const float* bond = (const float*)d_in[2];
  const float* wi   = (const float*)d_in[3];
  const float* bi   = (const float*)d_in[4];
  const float* wm   = (const float*)d_in[5];
  const float* bm   = (const float*)d_in[6];
  float* out = (float*)d_out;
  (void)d_ws; (void)ws_size;

  k_prep<<<(DDIM * K2 + 255) / 256, 256, 0, stream>>>(wi);
  k_pass1<<<NB1, 256, 0, stream>>>(x, he, bond, bi);
  k_mreduce<<<DDIM, 256, 0, stream>>>();
  k_msg<<<1, 128, 0, stream>>>(wm, bm);
  k_pass2<<<P2_BLOCKS, 256, 0, stream>>>(out);
}

// Round 3
// 255.028 us; speedup vs baseline: 2.5047x; 2.5047x over previous
//
#include <hip/hip_runtime.h>
#include <stdint.h>
#include <stddef.h>

// Problem constants (fixed by setup_inputs)
#define N_ROWS 500000
#define DDIM   128
#define K2     256      // 2*D
#define KBOND  32
#define TILE_ROWS 64
#define NT ((N_ROWS + TILE_ROWS - 1) / TILE_ROWS)   // 7813
#define NB1 2048        // pass1 grid (grid-stride over tiles)
#define P2_BLOCKS 2048

typedef float  f32x4  __attribute__((ext_vector_type(4)));
typedef __bf16 bf16x8 __attribute__((ext_vector_type(8)));
typedef __bf16 bf16x4 __attribute__((ext_vector_type(4)));

// ---- module-scope device scratch: no dependence on d_ws/ws_size ----
__device__ __bf16 g_wbf[DDIM * K2];                    // 64 KiB  (W_i_w bf16, [d][k])
__device__ float  g_partials[NB1 * DDIM];              // 1 MiB
__device__ float  g_m[DDIM];
__device__ float  g_msg[DDIM];
__device__ __bf16 g_hn[(size_t)N_ROWS * DDIM];         // 128 MiB (h_n bf16)

// ---- kernel 1: W_i_w f32 -> bf16 (natural [d][k] layout) ----
__global__ void k_prep(const float* __restrict__ w) {
  int t = blockIdx.x * blockDim.x + threadIdx.x;
  if (t < DDIM * K2) g_wbf[t] = (__bf16)w[t];          // RNE convert
}

// ---- kernel 2: fused h_n GEMM + m partial accumulation ----
// 512 threads = 8 waves. Block tile: 64 rows (n) x 128 cols (d).
// MFMA operands SWAPPED vs usual: A = W (rows=d), B = x-data (cols=n), so
// D[r=d][c=n]: lane l -> n = l&15, d = 16*w + 4*(l>>4) + reg. Lane's 4 acc
// values are 4 CONSECUTIVE d at one n -> 8-B bf16x4 h_n stores.
// A/B k-maps are loaded with the IDENTICAL (g,e)->k map (k = 32ks+8g+e), so
// any internal hardware k-permutation cancels (verified working in round 2).
__global__ __launch_bounds__(512)
void k_pass1(const float* __restrict__ x, const float* __restrict__ he,
             const float* __restrict__ bond, const float* __restrict__ bias)
{
  // A-tile LDS: 64 rows x 256 k bf16, row stride 512 B, XOR-swizzled:
  // byte(r,k) = r*512 + ((2k) ^ ((r&7)<<4))   [G4's documented conflict fix]
  __shared__ __align__(16) unsigned char a_lds[TILE_ROWS * 512];   // 32 KiB
  __shared__ float s_lds[TILE_ROWS];
  __shared__ float mred[DDIM];

  const int tid  = threadIdx.x;
  const int w    = tid >> 6;        // wave 0..7: owns d in [16w, 16w+16)
  const int lane = tid & 63;
  const int l15  = lane & 15;
  const int g    = lane >> 4;       // 0..3

  // W A-fragments for this wave, ALL K, in registers (loaded once): 32 VGPRs
  bf16x8 wfrag[8];
  #pragma unroll
  for (int ks = 0; ks < 8; ++ks)
    wfrag[ks] = *(const bf16x8*)(g_wbf + (size_t)(16 * w + l15) * K2 + ks * 32 + 8 * g);

  const int d0 = 16 * w + 4 * g;            // lane's 4 consecutive output cols
  const f32x4 bv = *(const f32x4*)(bias + d0);

  f32x4 macc = (f32x4)(0.f);                // m partial for d0..d0+3

  for (int tile = blockIdx.x; tile < NT; tile += gridDim.x) {
    const int rb_blk = tile * TILE_ROWS;

    // ---- stage A-tile: 64 rows x (x:128 | he:128) f32 -> bf16 LDS ----
    #pragma unroll
    for (int it = 0; it < 4; ++it) {
      const int r  = it * 16 + (tid >> 5);          // 0..63
      const int k4 = (tid & 31) * 4;                // f32 col within 128
      int n  = rb_blk + r;
      int nc = n < N_ROWS ? n : (N_ROWS - 1);       // clamp (s=0 kills OOB)
      f32x4 xv = *(const f32x4*)(x  + (size_t)nc * DDIM + k4);
      f32x4 hv = *(const f32x4*)(he + (size_t)nc * DDIM + k4);
      bf16x4 xb, hb;
      #pragma unroll
      for (int i = 0; i < 4; ++i) { xb[i] = (__bf16)xv[i]; hb[i] = (__bf16)hv[i]; }
      const int sw = (r & 7) << 4;
      *(bf16x4*)(a_lds + r * 512 + ((2 * k4) ^ sw))         = xb;
      *(bf16x4*)(a_lds + r * 512 + ((2 * (128 + k4)) ^ sw)) = hb;
    }

    // ---- s[n] = sum_k bond[k][n] ----
    if (tid < TILE_ROWS) {
      int n = rb_blk + tid;
      float s = 0.f;
      if (n < N_ROWS) {
        #pragma unroll
        for (int k = 0; k < KBOND; ++k) s += bond[(size_t)k * N_ROWS + n];
      }
      s_lds[tid] = s;
    }
    __syncthreads();

    // ---- MFMA: acc[nf] over 4 n-fragments, K unrolled ----
    f32x4 acc[4];
    #pragma unroll
    for (int i = 0; i < 4; ++i) acc[i] = (f32x4)(0.f);

    #pragma unroll
    for (int ks = 0; ks < 8; ++ks) {
      bf16x8 bfrag[4];
      #pragma unroll
      for (int nf = 0; nf < 4; ++nf) {
        const int r = 16 * nf + l15;
        bfrag[nf] = *(const bf16x8*)(a_lds + r * 512 +
                                     ((64 * ks + 16 * g) ^ ((r & 7) << 4)));
      }
      #pragma unroll
      for (int nf = 0; nf < 4; ++nf)
        acc[nf] = __builtin_amdgcn_mfma_f32_16x16x32_bf16(wfrag[ks], bfrag[nf],
                                                          acc[nf], 0, 0, 0);
    }

    // ---- epilogue: bias+relu, 8-B h_n store, m partial ----
    #pragma unroll
    for (int nf = 0; nf < 4; ++nf) {
      const int lr = 16 * nf + l15;
      const int n  = rb_blk + lr;
      const float sn = s_lds[lr];
      f32x4 h;
      #pragma unroll
      for (int i = 0; i < 4; ++i) {
        float v = acc[nf][i] + bv[i];
        h[i] = v > 0.f ? v : 0.f;
      }
      macc += sn * h;
      if (n < N_ROWS) {
        bf16x4 hb;
        #pragma unroll
        for (int i = 0; i < 4; ++i) hb[i] = (__bf16)h[i];
        *(bf16x4*)(g_hn + (size_t)n * DDIM + d0) = hb;
      }
    }
    __syncthreads();   // protect a_lds/s_lds for next tile's staging
  }

  // ---- m partial: sum over the 16 l15 lanes (same d), write block partial ----
  #pragma unroll
  for (int off = 1; off <= 8; off <<= 1) {
    #pragma unroll
    for (int i = 0; i < 4; ++i) macc[i] += __shfl_xor(macc[i], off, 64);
  }
  if (l15 == 0) {
    #pragma unroll
    for (int i = 0; i < 4; ++i) mred[d0 + i] = macc[i];   // waves own disjoint d
  }
  __syncthreads();
  if (tid < DDIM)
    g_partials[(size_t)blockIdx.x * DDIM + tid] = mred[tid];
}

// ---- kernel 3: reduce partials -> m[128] (one block per d) ----
__global__ void k_mreduce() {
  const int d = blockIdx.x;
  float s = 0.f;
  for (int i = threadIdx.x; i < NB1; i += 256) s += g_partials[(size_t)i * DDIM + d];
  #pragma unroll
  for (int off = 32; off >= 1; off >>= 1) s += __shfl_down(s, off, 64);
  __shared__ float red[4];
  if ((threadIdx.x & 63) == 0) red[threadIdx.x >> 6] = s;
  __syncthreads();
  if (threadIdx.x == 0) g_m[d] = red[0] + red[1] + red[2] + red[3];
}

// ---- kernel 4: msg[d] = b_m[d] + sum_j m[j] * W_m_w[d][j] ----
__global__ void k_msg(const float* __restrict__ wm, const float* __restrict__ bm) {
  __shared__ float ms[DDIM];
  if (threadIdx.x < DDIM) ms[threadIdx.x] = g_m[threadIdx.x];
  __syncthreads();
  const int d = threadIdx.x;
  if (d < DDIM) {
    float acc = bm[d];
    #pragma unroll 8
    for (int j = 0; j < DDIM; ++j) acc += ms[j] * wm[(size_t)d * DDIM + j];
    g_msg[d] = acc;
  }
}

// ---- kernel 5: out = relu(h_n + msg) ----
__global__ __launch_bounds__(256)
void k_pass2(float* __restrict__ out)
{
  __shared__ float ms[DDIM];
  if (threadIdx.x < DDIM) ms[threadIdx.x] = g_msg[threadIdx.x];
  __syncthreads();
  const size_t total = (size_t)N_ROWS * DDIM / 8;   // 8 elems per chunk
  for (size_t c = (size_t)blockIdx.x * blockDim.x + threadIdx.x; c < total;
       c += (size_t)gridDim.x * blockDim.x) {
    const size_t base = c * 8;
    const int col0 = (int)(base & (DDIM - 1));
    bf16x8 hv = *(const bf16x8*)(g_hn + base);
    f32x4 o0, o1;
    #pragma unroll
    for (int i = 0; i < 4; ++i) {
      float a = (float)hv[i]     + ms[col0 + i];
      float b = (float)hv[4 + i] + ms[col0 + 4 + i];
      o0[i] = a > 0.f ? a : 0.f;
      o1[i] = b > 0.f ? b : 0.f;
    }
    *(f32x4*)(out + base)     = o0;
    *(f32x4*)(out + base + 4) = o1;
  }
}

extern "C" void kernel_launch(void* const* d_in, const int* in_sizes, int n_in,
                              void* d_out, int out_size, void* d_ws, size_t ws_size,
                              hipStream_t stream) {
  const float* x    = (const float*)d_in[0];
  const float* he   = (const float*)d_in[1];
  const float* bond = (const float*)d_in[2];
  const float* wi   = (const float*)d_in[3];
  const float* bi   = (const float*)d_in[4];
  const float* wm   = (const float*)d_in[5];
  const float* bm   = (const float*)d_in[6];
  float* out = (float*)d_out;
  (void)d_ws; (void)ws_size;

  k_prep<<<(DDIM * K2 + 255) / 256, 256, 0, stream>>>(wi);
  k_pass1<<<NB1, 512, 0, stream>>>(x, he, bond, bi);
  k_mreduce<<<DDIM, 256, 0, stream>>>();
  k_msg<<<1, 128, 0, stream>>>(wm, bm);
  k_pass2<<<P2_BLOCKS, 256, 0, stream>>>(out);
}